// Round 1
// baseline (863.667 us; speedup 1.0000x reference)
//
#include <hip/hip_runtime.h>

#define B_   8
#define C_   96
#define H_   160
#define W_   320
#define MH   4
#define MW   4
#define ND   9            // offsets per dim (2*4+1)
#define NDD  81           // total offsets
#define TH   16
#define TW   32
#define HR   (TH + 2*MH)  // 24 halo rows
#define HWW  (TW + 2*MW)  // 40 halo cols
#define KC   8            // channels per LDS chunk
#define NCH  (C_/KC)      // 12 chunks
#define F1S  36           // f1 LDS row stride (padded: 36%32=4 spreads bank phases)
#define F2S  44           // f2 LDS row stride (padded: 44%32=12 spreads bank phases)
#define F1PLANE (TH*F1S)          // 576 words per channel
#define F2PLANE (HR*F2S)          // 1056 words per channel
#define F2OFF   (KC*F1PLANE)      // 4608
#define LDSWORDS (KC*(F1PLANE+F2PLANE))  // 13056 words = 52224 B

__global__ __launch_bounds__(576) void corr_kernel(
    const float* __restrict__ f1g,
    const float* __restrict__ f2g,
    float* __restrict__ out)
{
    __shared__ float lds[LDSWORDS];

    const int tid  = threadIdx.x;
    const int wave = tid >> 6;        // dh index 0..8 (this wave's row offset)
    const int lane = tid & 63;
    const int row  = lane >> 2;       // 0..15 (output row within tile)
    const int colb = (lane & 3) * 8;  // 0,8,16,24 (output col base; 8 px/thread)

    const int x0 = blockIdx.x * TW;
    const int y0 = blockIdx.y * TH;
    const int b  = blockIdx.z;
    const int HWi = H_ * W_;

    // ---------------- staging descriptors (prologue-only math) ----------------
    // f1: threads 0..511 stage one word per channel (row t/32, col t%32). In-bounds always.
    const bool doF1  = tid < (TH * TW);
    const int  f1r   = tid >> 5;
    const int  f1c   = tid & 31;
    const int  f1goff = ((b * C_) * H_ + (y0 + f1r)) * W_ + x0 + f1c; // + c*HW
    const int  f1loff = f1r * F1S + f1c;

    // f2 halo (24x40 = 960 words/channel), pass A: word tid (all 576 threads)
    const int  rA = tid / HWW, cA = tid % HWW;
    const int  gyA = y0 - MH + rA, gxA = x0 - MW + cA;
    const bool inbA = (gyA >= 0) && (gyA < H_) && (gxA >= 0) && (gxA < W_);
    const int  f2goffA = ((b * C_) * H_ + gyA) * W_ + gxA;
    const int  f2loffA = rA * F2S + cA;

    // pass B: word 576+tid for tid<384 (wave-uniform predicate: waves 0..5)
    const bool doB = tid < (HR * HWW - TH * TW - 64); // 960-576=384
    const int  wB = TH * TW + 64 + tid;               // 576+tid
    const int  rB = wB / HWW, cB = wB % HWW;
    const int  gyB = y0 - MH + rB, gxB = x0 - MW + cB;
    const bool inbB = doB && (gyB >= 0) && (gyB < H_) && (gxB >= 0) && (gxB < W_);
    const int  f2goffB = ((b * C_) * H_ + gyB) * W_ + gxB;
    const int  f2loffB = rB * F2S + cB;

    // compute-side LDS read bases (word offsets; all 16B-aligned)
    const int f1readbase = row * F1S + colb;
    const int f2readbase = (row + wave) * F2S + colb;  // halo row = out row + dh

    float acc[8][ND];
#pragma unroll
    for (int i = 0; i < 8; ++i)
#pragma unroll
        for (int d = 0; d < ND; ++d) acc[i][d] = 0.f;

    // staging registers (chunk in flight)
    float s1[KC], s2a[KC], s2b[KC];

    // ---- preload chunk 0 ----
#pragma unroll
    for (int c = 0; c < KC; ++c) {
        float v1 = 0.f, va = 0.f, vb = 0.f;
        if (doF1) v1 = f1g[f1goff + c * HWi];
        if (inbA) va = f2g[f2goffA + c * HWi];
        if (inbB) vb = f2g[f2goffB + c * HWi];
        s1[c] = v1; s2a[c] = va; s2b[c] = vb;
    }

#pragma unroll 1
    for (int ch = 0; ch < NCH; ++ch) {
        __syncthreads();  // all waves done reading previous chunk's LDS
        // commit staged regs -> LDS (compiler inserts vmcnt wait on dependence)
#pragma unroll
        for (int c = 0; c < KC; ++c) {
            if (doF1) lds[c * F1PLANE + f1loff] = s1[c];
            lds[F2OFF + c * F2PLANE + f2loffA] = s2a[c];
            if (doB)  lds[F2OFF + c * F2PLANE + f2loffB] = s2b[c];
        }
        __syncthreads();
        // prefetch next chunk (issued before compute; latency hidden under FMAs)
        if (ch + 1 < NCH) {
            const int cb = (ch + 1) * KC;
#pragma unroll
            for (int c = 0; c < KC; ++c) {
                float v1 = 0.f, va = 0.f, vb = 0.f;
                if (doF1) v1 = f1g[f1goff + (cb + c) * HWi];
                if (inbA) va = f2g[f2goffA + (cb + c) * HWi];
                if (inbB) vb = f2g[f2goffB + (cb + c) * HWi];
                s1[c] = v1; s2a[c] = va; s2b[c] = vb;
            }
        }
        // compute current chunk
#pragma unroll
        for (int c = 0; c < KC; ++c) {
            const float4* p1 = (const float4*)&lds[c * F1PLANE + f1readbase];
            const float4  a0 = p1[0], a1 = p1[1];
            const float4* p2 = (const float4*)&lds[F2OFF + c * F2PLANE + f2readbase];
            const float4  b0 = p2[0], b1 = p2[1], b2 = p2[2], b3 = p2[3];
            const float f1v[8]  = {a0.x,a0.y,a0.z,a0.w,a1.x,a1.y,a1.z,a1.w};
            const float f2v[16] = {b0.x,b0.y,b0.z,b0.w,b1.x,b1.y,b1.z,b1.w,
                                   b2.x,b2.y,b2.z,b2.w,b3.x,b3.y,b3.z,b3.w};
#pragma unroll
            for (int i = 0; i < 8; ++i)
#pragma unroll
                for (int d = 0; d < ND; ++d)
                    acc[i][d] = fmaf(f1v[i], f2v[i + d], acc[i][d]);
        }
    }

    // ---- epilogue: out[b, wave*9+d, y0+row, x0+colb+i] ----
    const int gy = y0 + row;
    const int gx = x0 + colb;
#pragma unroll
    for (int d = 0; d < ND; ++d) {
        float4 v0, v1;
        v0.x = acc[0][d]; v0.y = acc[1][d]; v0.z = acc[2][d]; v0.w = acc[3][d];
        v1.x = acc[4][d]; v1.y = acc[5][d]; v1.z = acc[6][d]; v1.w = acc[7][d];
        float* op = out + (((long)(b * NDD + wave * ND + d) * H_ + gy)) * W_ + gx;
        *(float4*)(op)     = v0;
        *(float4*)(op + 4) = v1;
    }
}

extern "C" void kernel_launch(void* const* d_in, const int* in_sizes, int n_in,
                              void* d_out, int out_size, void* d_ws, size_t ws_size,
                              hipStream_t stream)
{
    const float* f1 = (const float*)d_in[0];
    const float* f2 = (const float*)d_in[1];
    float* out = (float*)d_out;
    dim3 grid(W_ / TW, H_ / TH, B_);  // 10 x 10 x 8 = 800 blocks
    corr_kernel<<<grid, 576, 0, stream>>>(f1, f2, out);
}